// Round 1
// baseline (551.550 us; speedup 1.0000x reference)
//
#include <hip/hip_runtime.h>
#include <hip/hip_bf16.h>

// Problem constants (fixed by the reference)
#define BB 8      // batch
#define NQ 196    // image tokens (queries)
#define NKK 128   // sentence tokens (keys)
#define HH 8      // heads
#define DH 1024   // per-head dim
#define DI 1024   // image embed dim
#define DL 768    // sentence embed dim
#define HD 8192   // HH*DH

typedef __attribute__((ext_vector_type(8))) short short8;
typedef __attribute__((ext_vector_type(4))) float f32x4;

__device__ inline unsigned short f2bf(float f) {
  // RTNE f32 -> bf16 (inputs finite)
  unsigned int x = __float_as_uint(f);
  unsigned int r = (x + 0x7fffu + ((x >> 16) & 1u)) >> 16;
  return (unsigned short)r;
}

// ---------------- transpose f32[R][C] -> bf16[C][R] ----------------
__global__ __launch_bounds__(256) void k_transpose_f32_bf16(
    const float* __restrict__ in, unsigned short* __restrict__ out, int R, int C) {
  __shared__ float tile[32][33];
  int c0 = blockIdx.x * 32, r0 = blockIdx.y * 32;
  int tx = threadIdx.x & 31, ty = threadIdx.x >> 5;  // 32 x 8
#pragma unroll
  for (int k = 0; k < 32; k += 8)
    tile[ty + k][tx] = in[(size_t)(r0 + ty + k) * C + (c0 + tx)];
  __syncthreads();
#pragma unroll
  for (int k = 0; k < 32; k += 8)
    out[(size_t)(c0 + ty + k) * R + (r0 + tx)] = f2bf(tile[tx][ty + k]);
}

// ------------- batched transpose of V: [b*128+key][h*1024+d] -> Vt[z][d][key] -------------
__global__ __launch_bounds__(256) void k_transpose_v(
    const unsigned short* __restrict__ Vp, unsigned short* __restrict__ Vt) {
  __shared__ unsigned short tile[32][34];
  int z = blockIdx.z, b = z >> 3, h = z & 7;
  const unsigned short* in = Vp + (size_t)b * NKK * HD + (size_t)h * DH;
  unsigned short* out = Vt + (size_t)z * DH * NKK;
  int d0 = blockIdx.x * 32, k0 = blockIdx.y * 32;
  int tx = threadIdx.x & 31, ty = threadIdx.x >> 5;
#pragma unroll
  for (int k = 0; k < 32; k += 8)
    tile[ty + k][tx] = in[(size_t)(k0 + ty + k) * HD + (d0 + tx)];
  __syncthreads();
#pragma unroll
  for (int k = 0; k < 32; k += 8)
    out[(size_t)(d0 + ty + k) * NKK + (k0 + tx)] = tile[tx][ty + k];
}

// ---------------- generic batched MFMA GEMM ----------------
// C[m][n] = sum_k A[m][k] * Bt[n][k]   (Bt is [N][K] bf16)
// batch z -> (zb = z/8, zh = z%8); offsets in ELEMENTS.
// BM=BN=128, BK=64; 256 threads = 4 waves, each wave a 64x64 sub-tile (4x4 MFMA frags).
template<bool A_BF16, bool C_BF16, bool RESID>
__global__ __launch_bounds__(256, 2) void k_gemm(
    const void* __restrict__ Aptr, const unsigned short* __restrict__ Bt,
    void* __restrict__ Cptr, const float* __restrict__ resid,
    int M, int N, int K, int lda, int ldb, int ldc,
    long aSB, long aSH, long bSB, long bSH, long cSB, long cSH) {
  __shared__ unsigned short As[128][72];  // +8 pad: breaks 16-way bank conflicts
  __shared__ unsigned short Bs[128][72];

  const int tid = threadIdx.x;
  const int lane = tid & 63;
  const int wid = tid >> 6;
  const int wm = wid >> 1, wn = wid & 1;
  const int m_base = blockIdx.y * 128;
  const int n_base = blockIdx.x * 128;
  const int z = blockIdx.z, zb = z >> 3, zh = z & 7;
  const size_t aOff = (size_t)zb * aSB + (size_t)zh * aSH;
  const size_t bOff = (size_t)zb * bSB + (size_t)zh * bSH;
  const size_t cOff = (size_t)zb * cSB + (size_t)zh * cSH;

  f32x4 acc[4][4] = {};

  const int sr = tid >> 3;        // 0..31 (row within pass)
  const int sc = (tid & 7) * 8;   // 0..56 (k-col, 8 elems/thread)

  for (int k0 = 0; k0 < K; k0 += 64) {
#pragma unroll
    for (int p = 0; p < 4; ++p) {
      int r = p * 32 + sr;
      // ---- A tile (clamp rows >= M to a valid row; those C rows are never stored) ----
      int gm = m_base + r; gm = (gm < M) ? gm : (M - 1);
      short8 va;
      if constexpr (A_BF16) {
        const unsigned short* ap = (const unsigned short*)Aptr + aOff + (size_t)gm * lda + (k0 + sc);
        va = *reinterpret_cast<const short8*>(ap);
      } else {
        const float* ap = (const float*)Aptr + aOff + (size_t)gm * lda + (k0 + sc);
        float4 x = *reinterpret_cast<const float4*>(ap);
        float4 y = *reinterpret_cast<const float4*>(ap + 4);
        va[0] = (short)f2bf(x.x); va[1] = (short)f2bf(x.y);
        va[2] = (short)f2bf(x.z); va[3] = (short)f2bf(x.w);
        va[4] = (short)f2bf(y.x); va[5] = (short)f2bf(y.y);
        va[6] = (short)f2bf(y.z); va[7] = (short)f2bf(y.w);
      }
      *reinterpret_cast<short8*>(&As[r][sc]) = va;
      // ---- B tile (N is always a multiple of 128 in this pipeline) ----
      int gn = n_base + r;
      const unsigned short* bp = Bt + bOff + (size_t)gn * ldb + (k0 + sc);
      *reinterpret_cast<short8*>(&Bs[r][sc]) = *reinterpret_cast<const short8*>(bp);
    }
    __syncthreads();
#pragma unroll
    for (int kk = 0; kk < 2; ++kk) {
      const int ko = kk * 32 + (lane >> 4) * 8;
      short8 af[4], bf[4];
#pragma unroll
      for (int mi = 0; mi < 4; ++mi)
        af[mi] = *reinterpret_cast<const short8*>(&As[wm * 64 + mi * 16 + (lane & 15)][ko]);
#pragma unroll
      for (int ni = 0; ni < 4; ++ni)
        bf[ni] = *reinterpret_cast<const short8*>(&Bs[wn * 64 + ni * 16 + (lane & 15)][ko]);
#pragma unroll
      for (int mi = 0; mi < 4; ++mi)
#pragma unroll
        for (int ni = 0; ni < 4; ++ni)
          acc[mi][ni] = __builtin_amdgcn_mfma_f32_16x16x32_bf16(af[mi], bf[ni], acc[mi][ni], 0, 0, 0);
    }
    __syncthreads();
  }

  // epilogue: C/D layout col = lane&15, row = (lane>>4)*4 + reg  [learn_hip m89/m91]
  const int rq = (lane >> 4) * 4;
  const int cq = lane & 15;
#pragma unroll
  for (int mi = 0; mi < 4; ++mi) {
#pragma unroll
    for (int ni = 0; ni < 4; ++ni) {
      int col = n_base + wn * 64 + ni * 16 + cq;
#pragma unroll
      for (int i = 0; i < 4; ++i) {
        int row = m_base + wm * 64 + mi * 16 + rq + i;
        if (row < M) {
          float val = acc[mi][ni][i];
          if constexpr (RESID) val += resid[(size_t)row * ldc + col];
          size_t off = cOff + (size_t)row * ldc + col;
          if constexpr (C_BF16) ((unsigned short*)Cptr)[off] = f2bf(val);
          else                  ((float*)Cptr)[off] = val;
        }
      }
    }
  }
}

// ---------------- masked softmax over 128 keys, one wave per row ----------------
__global__ __launch_bounds__(256) void k_softmax(
    const float* __restrict__ S, unsigned short* __restrict__ P, const int* __restrict__ mask) {
  int row = blockIdx.x * 4 + (threadIdx.x >> 6);
  if (row >= BB * HH * NQ) return;
  int lane = threadIdx.x & 63;
  int b = row / (HH * NQ);
  const float* s = S + (size_t)row * NKK;
  float s0 = s[lane] * 0.03125f;        // 1/sqrt(1024)
  float s1 = s[lane + 64] * 0.03125f;
  const int* mrow = mask + b * NKK;
  if (mrow[lane] == 0)      s0 = -1e30f;
  if (mrow[lane + 64] == 0) s1 = -1e30f;
  float mx = fmaxf(s0, s1);
#pragma unroll
  for (int d = 32; d; d >>= 1) mx = fmaxf(mx, __shfl_xor(mx, d));
  float e0 = __expf(s0 - mx), e1 = __expf(s1 - mx);
  float sum = e0 + e1;
#pragma unroll
  for (int d = 32; d; d >>= 1) sum += __shfl_xor(sum, d);
  float inv = 1.0f / sum;
  P[(size_t)row * NKK + lane]      = f2bf(e0 * inv);
  P[(size_t)row * NKK + lane + 64] = f2bf(e1 * inv);
}

// ---------------- LayerNorm over 1024, one block per row ----------------
__global__ __launch_bounds__(256) void k_layernorm(
    const float* __restrict__ X, const float* __restrict__ gamma,
    const float* __restrict__ beta, float* __restrict__ out) {
  int row = blockIdx.x;
  const float* x = X + (size_t)row * DI;
  int tid = threadIdx.x;
  float v[4], sum = 0.f, sq = 0.f;
#pragma unroll
  for (int i = 0; i < 4; ++i) { v[i] = x[tid + i * 256]; sum += v[i]; sq += v[i] * v[i]; }
#pragma unroll
  for (int d = 32; d; d >>= 1) { sum += __shfl_xor(sum, d); sq += __shfl_xor(sq, d); }
  __shared__ float ssum[4], ssq[4];
  int w = tid >> 6;
  if ((tid & 63) == 0) { ssum[w] = sum; ssq[w] = sq; }
  __syncthreads();
  sum = ssum[0] + ssum[1] + ssum[2] + ssum[3];
  sq  = ssq[0]  + ssq[1]  + ssq[2]  + ssq[3];
  float mean = sum * (1.0f / DI);
  float var  = sq * (1.0f / DI) - mean * mean;
  float rstd = rsqrtf(var + 1e-5f);
  float* o = out + (size_t)row * DI;
#pragma unroll
  for (int i = 0; i < 4; ++i) {
    int c = tid + i * 256;
    o[c] = (v[i] - mean) * rstd * gamma[c] + beta[c];
  }
}

extern "C" void kernel_launch(void* const* d_in, const int* in_sizes, int n_in,
                              void* d_out, int out_size, void* d_ws, size_t ws_size,
                              hipStream_t stream) {
  const float* img   = (const float*)d_in[0];
  const float* sent  = (const float*)d_in[1];
  const int*   mask  = (const int*)d_in[2];
  const float* Wq    = (const float*)d_in[3];
  const float* Wk    = (const float*)d_in[4];
  const float* Wv    = (const float*)d_in[5];
  const float* Wo    = (const float*)d_in[6];
  const float* gamma = (const float*)d_in[7];
  const float* beta  = (const float*)d_in[8];
  float* out = (float*)d_out;

  // workspace layout (~118 MB, lifetime-aliased)
  char* ws = (char*)d_ws;
  size_t o = 0;
  auto give = [&](size_t bytes) { char* p = ws + o; o += (bytes + 255) & ~(size_t)255; return p; };
  unsigned short* WqT = (unsigned short*)give((size_t)HD * DI * 2);       // [8192][1024]
  unsigned short* WkT = (unsigned short*)give((size_t)HD * DL * 2);       // [8192][768]
  unsigned short* WvT = (unsigned short*)give((size_t)HD * DL * 2);       // [8192][768]
  unsigned short* WoT = (unsigned short*)give((size_t)DI * HD * 2);       // [1024][8192]
  unsigned short* Qb  = (unsigned short*)give((size_t)BB * NQ * HD * 2);  // [1568][8192]
  unsigned short* Kb  = (unsigned short*)give((size_t)BB * NKK * HD * 2); // [1024][8192]
  unsigned short* Vb  = (unsigned short*)give((size_t)BB * NKK * HD * 2); // [1024][8192]
  // lifetime aliases (producers run strictly after the aliased buffer is dead)
  unsigned short* Vt  = WqT;             // [64][1024][128] bf16 == 16.78 MB (WqT dead after Q-proj)
  float*          S   = (float*)WkT;     // [64][196][128] f32 = 6.4 MB (WkT dead after K-proj)
  unsigned short* P   = WvT;             // [64][196][128] bf16 = 3.2 MB (WvT dead after V-proj)
  unsigned short* ctx = Qb;              // [1568][8192] bf16 (Q dead after score GEMM)
  float*          Oac = (float*)Kb;      // [1568][1024] f32 = 6.4 MB (K dead after score GEMM)

  dim3 tb(256);

  // 0) weight transpose+convert -> bf16 [N][K]
  k_transpose_f32_bf16<<<dim3(HD / 32, DI / 32), tb, 0, stream>>>(Wq, WqT, DI, HD);
  k_transpose_f32_bf16<<<dim3(HD / 32, DL / 32), tb, 0, stream>>>(Wk, WkT, DL, HD);
  k_transpose_f32_bf16<<<dim3(HD / 32, DL / 32), tb, 0, stream>>>(Wv, WvT, DL, HD);
  k_transpose_f32_bf16<<<dim3(DI / 32, HD / 32), tb, 0, stream>>>(Wo, WoT, HD, DI);

  // 1) Q = img @ Wq  [1568 x 8192], K = sent @ Wk, V = sent @ Wv  [1024 x 8192]
  k_gemm<false, true, false><<<dim3(HD / 128, (BB * NQ + 127) / 128, 1), tb, 0, stream>>>(
      img, WqT, Qb, nullptr, BB * NQ, HD, DI, DI, DI, HD, 0, 0, 0, 0, 0, 0);
  k_gemm<false, true, false><<<dim3(HD / 128, (BB * NKK) / 128, 1), tb, 0, stream>>>(
      sent, WkT, Kb, nullptr, BB * NKK, HD, DL, DL, DL, HD, 0, 0, 0, 0, 0, 0);
  k_gemm<false, true, false><<<dim3(HD / 128, (BB * NKK) / 128, 1), tb, 0, stream>>>(
      sent, WvT, Vb, nullptr, BB * NKK, HD, DL, DL, DL, HD, 0, 0, 0, 0, 0, 0);

  // 2) V -> Vt [z][d][key]
  k_transpose_v<<<dim3(DH / 32, NKK / 32, BB * HH), tb, 0, stream>>>(Vb, Vt);

  // 3) S[z] = Q_bh @ K_bh^T  (batched over 64 (b,h))
  k_gemm<true, false, false><<<dim3(NKK / 128, (NQ + 127) / 128, BB * HH), tb, 0, stream>>>(
      Qb, Kb, S, nullptr, NQ, NKK, DH, HD, HD, NKK,
      (long)NQ * HD, (long)DH, (long)NKK * HD, (long)DH, (long)HH * NQ * NKK, (long)NQ * NKK);

  // 4) P = softmax(S/32 masked)
  k_softmax<<<dim3(BB * HH * NQ / 4), tb, 0, stream>>>(S, P, mask);

  // 5) ctx[z] = P_bh @ V_bh  (via Vt as [d][key])
  k_gemm<true, true, false><<<dim3(DH / 128, (NQ + 127) / 128, BB * HH), tb, 0, stream>>>(
      P, Vt, ctx, nullptr, NQ, DH, NKK, NKK, NKK, HD,
      (long)HH * NQ * NKK, (long)NQ * NKK, (long)HH * DH * NKK, (long)DH * NKK,
      (long)NQ * HD, (long)DH);

  // 6) Oac = ctx @ Wo + img  [1568 x 1024] f32
  k_gemm<true, false, true><<<dim3(DI / 128, (BB * NQ + 127) / 128, 1), tb, 0, stream>>>(
      ctx, WoT, Oac, img, BB * NQ, DI, HD, HD, HD, DI, 0, 0, 0, 0, 0, 0);

  // 7) LayerNorm -> d_out
  k_layernorm<<<dim3(BB * NQ), tb, 0, stream>>>(Oac, gamma, beta, out);
}

// Round 2
// 350.508 us; speedup vs baseline: 1.5736x; 1.5736x over previous
//
#include <hip/hip_runtime.h>
#include <hip/hip_bf16.h>

// Problem constants (fixed by the reference)
#define BB 8      // batch
#define NQ 196    // image tokens (queries)
#define NKK 128   // sentence tokens (keys)
#define HH 8      // heads
#define DH 1024   // per-head dim
#define DI 1024   // image embed dim
#define DL 768    // sentence embed dim
#define HD 8192   // HH*DH
#define KSPLIT 4  // split-K factor for the out-projection GEMM

typedef __attribute__((ext_vector_type(8))) short short8;
typedef __attribute__((ext_vector_type(4))) float f32x4;

__device__ inline unsigned short f2bf(float f) {
  // RTNE f32 -> bf16 (inputs finite)
  unsigned int x = __float_as_uint(f);
  unsigned int r = (x + 0x7fffu + ((x >> 16) & 1u)) >> 16;
  return (unsigned short)r;
}

// ---------------- transpose f32[R][C] -> bf16[C][R] ----------------
__global__ __launch_bounds__(256) void k_transpose_f32_bf16(
    const float* __restrict__ in, unsigned short* __restrict__ out, int R, int C) {
  __shared__ float tile[32][33];
  int c0 = blockIdx.x * 32, r0 = blockIdx.y * 32;
  int tx = threadIdx.x & 31, ty = threadIdx.x >> 5;  // 32 x 8
#pragma unroll
  for (int k = 0; k < 32; k += 8)
    tile[ty + k][tx] = in[(size_t)(r0 + ty + k) * C + (c0 + tx)];
  __syncthreads();
#pragma unroll
  for (int k = 0; k < 32; k += 8)
    out[(size_t)(c0 + ty + k) * R + (r0 + tx)] = f2bf(tile[tx][ty + k]);
}

// ------------- batched transpose of V: [b*128+key][h*1024+d] -> Vt[z][d][key] -------------
__global__ __launch_bounds__(256) void k_transpose_v(
    const unsigned short* __restrict__ Vp, unsigned short* __restrict__ Vt) {
  __shared__ unsigned short tile[32][34];
  int z = blockIdx.z, b = z >> 3, h = z & 7;
  const unsigned short* in = Vp + (size_t)b * NKK * HD + (size_t)h * DH;
  unsigned short* out = Vt + (size_t)z * DH * NKK;
  int d0 = blockIdx.x * 32, k0 = blockIdx.y * 32;
  int tx = threadIdx.x & 31, ty = threadIdx.x >> 5;
#pragma unroll
  for (int k = 0; k < 32; k += 8)
    tile[ty + k][tx] = in[(size_t)(k0 + ty + k) * HD + (d0 + tx)];
  __syncthreads();
#pragma unroll
  for (int k = 0; k < 32; k += 8)
    out[(size_t)(d0 + ty + k) * NKK + (k0 + tx)] = tile[tx][ty + k];
}

// ---------------- generic batched MFMA GEMM ----------------
// C[m][n] = sum_k A[m][k] * Bt[n][k]   (Bt is [N][K] bf16)
// batch z -> (zb = z/8, zh = z%8); offsets in ELEMENTS.
// BM=BN=128, BK=64; 256 threads = 4 waves, each wave a 64x64 sub-tile (4x4 MFMA frags).
// Split-K usage: launch with gridDim.z = KSPLIT, aSH/bSH = k-chunk element offset,
// cSH = partial-buffer stride, and K = chunk depth.
template<bool A_BF16, bool C_BF16, bool RESID>
__global__ __launch_bounds__(256, 2) void k_gemm(
    const void* __restrict__ Aptr, const unsigned short* __restrict__ Bt,
    void* __restrict__ Cptr, const float* __restrict__ resid,
    int M, int N, int K, int lda, int ldb, int ldc,
    long aSB, long aSH, long bSB, long bSH, long cSB, long cSH) {
  __shared__ unsigned short As[128][72];  // +8 pad: breaks 16-way bank conflicts
  __shared__ unsigned short Bs[128][72];

  const int tid = threadIdx.x;
  const int lane = tid & 63;
  const int wid = tid >> 6;
  const int wm = wid >> 1, wn = wid & 1;
  const int m_base = blockIdx.y * 128;
  const int n_base = blockIdx.x * 128;
  const int z = blockIdx.z, zb = z >> 3, zh = z & 7;
  const size_t aOff = (size_t)zb * aSB + (size_t)zh * aSH;
  const size_t bOff = (size_t)zb * bSB + (size_t)zh * bSH;
  const size_t cOff = (size_t)zb * cSB + (size_t)zh * cSH;

  f32x4 acc[4][4] = {};

  const int sr = tid >> 3;        // 0..31 (row within pass)
  const int sc = (tid & 7) * 8;   // 0..56 (k-col, 8 elems/thread)

  for (int k0 = 0; k0 < K; k0 += 64) {
#pragma unroll
    for (int p = 0; p < 4; ++p) {
      int r = p * 32 + sr;
      // ---- A tile (clamp rows >= M to a valid row; those C rows are never stored) ----
      int gm = m_base + r; gm = (gm < M) ? gm : (M - 1);
      short8 va;
      if constexpr (A_BF16) {
        const unsigned short* ap = (const unsigned short*)Aptr + aOff + (size_t)gm * lda + (k0 + sc);
        va = *reinterpret_cast<const short8*>(ap);
      } else {
        const float* ap = (const float*)Aptr + aOff + (size_t)gm * lda + (k0 + sc);
        float4 x = *reinterpret_cast<const float4*>(ap);
        float4 y = *reinterpret_cast<const float4*>(ap + 4);
        va[0] = (short)f2bf(x.x); va[1] = (short)f2bf(x.y);
        va[2] = (short)f2bf(x.z); va[3] = (short)f2bf(x.w);
        va[4] = (short)f2bf(y.x); va[5] = (short)f2bf(y.y);
        va[6] = (short)f2bf(y.z); va[7] = (short)f2bf(y.w);
      }
      *reinterpret_cast<short8*>(&As[r][sc]) = va;
      // ---- B tile (N is always a multiple of 128 in this pipeline) ----
      int gn = n_base + r;
      const unsigned short* bp = Bt + bOff + (size_t)gn * ldb + (k0 + sc);
      *reinterpret_cast<short8*>(&Bs[r][sc]) = *reinterpret_cast<const short8*>(bp);
    }
    __syncthreads();
#pragma unroll
    for (int kk = 0; kk < 2; ++kk) {
      const int ko = kk * 32 + (lane >> 4) * 8;
      short8 af[4], bf[4];
#pragma unroll
      for (int mi = 0; mi < 4; ++mi)
        af[mi] = *reinterpret_cast<const short8*>(&As[wm * 64 + mi * 16 + (lane & 15)][ko]);
#pragma unroll
      for (int ni = 0; ni < 4; ++ni)
        bf[ni] = *reinterpret_cast<const short8*>(&Bs[wn * 64 + ni * 16 + (lane & 15)][ko]);
#pragma unroll
      for (int mi = 0; mi < 4; ++mi)
#pragma unroll
        for (int ni = 0; ni < 4; ++ni)
          acc[mi][ni] = __builtin_amdgcn_mfma_f32_16x16x32_bf16(af[mi], bf[ni], acc[mi][ni], 0, 0, 0);
    }
    __syncthreads();
  }

  // epilogue: C/D layout col = lane&15, row = (lane>>4)*4 + reg  [learn_hip m89/m91]
  const int rq = (lane >> 4) * 4;
  const int cq = lane & 15;
#pragma unroll
  for (int mi = 0; mi < 4; ++mi) {
#pragma unroll
    for (int ni = 0; ni < 4; ++ni) {
      int col = n_base + wn * 64 + ni * 16 + cq;
#pragma unroll
      for (int i = 0; i < 4; ++i) {
        int row = m_base + wm * 64 + mi * 16 + rq + i;
        if (row < M) {
          float val = acc[mi][ni][i];
          if constexpr (RESID) val += resid[(size_t)row * ldc + col];
          size_t off = cOff + (size_t)row * ldc + col;
          if constexpr (C_BF16) ((unsigned short*)Cptr)[off] = f2bf(val);
          else                  ((float*)Cptr)[off] = val;
        }
      }
    }
  }
}

// ---------------- masked softmax over 128 keys, one wave per row ----------------
__global__ __launch_bounds__(256) void k_softmax(
    const float* __restrict__ S, unsigned short* __restrict__ P, const int* __restrict__ mask) {
  int row = blockIdx.x * 4 + (threadIdx.x >> 6);
  if (row >= BB * HH * NQ) return;
  int lane = threadIdx.x & 63;
  int b = row / (HH * NQ);
  const float* s = S + (size_t)row * NKK;
  float s0 = s[lane] * 0.03125f;        // 1/sqrt(1024)
  float s1 = s[lane + 64] * 0.03125f;
  const int* mrow = mask + b * NKK;
  if (mrow[lane] == 0)      s0 = -1e30f;
  if (mrow[lane + 64] == 0) s1 = -1e30f;
  float mx = fmaxf(s0, s1);
#pragma unroll
  for (int d = 32; d; d >>= 1) mx = fmaxf(mx, __shfl_xor(mx, d));
  float e0 = __expf(s0 - mx), e1 = __expf(s1 - mx);
  float sum = e0 + e1;
#pragma unroll
  for (int d = 32; d; d >>= 1) sum += __shfl_xor(sum, d);
  float inv = 1.0f / sum;
  P[(size_t)row * NKK + lane]      = f2bf(e0 * inv);
  P[(size_t)row * NKK + lane + 64] = f2bf(e1 * inv);
}

// ------- fused split-K reduce + residual + LayerNorm over 1024, one block per row -------
__global__ __launch_bounds__(256) void k_layernorm_red(
    const float* __restrict__ Parts,   // [KSPLIT][M][DI] f32 partials
    const float* __restrict__ resid,   // img [M][DI]
    const float* __restrict__ gamma, const float* __restrict__ beta,
    float* __restrict__ out, int M) {
  int row = blockIdx.x;
  int tid = threadIdx.x;
  const size_t stride = (size_t)M * DI;
  const float* p = Parts + (size_t)row * DI;
  const float* r = resid + (size_t)row * DI;
  float v[4], sum = 0.f, sq = 0.f;
#pragma unroll
  for (int i = 0; i < 4; ++i) {
    int c = tid + i * 256;
    float acc = r[c];
#pragma unroll
    for (int k = 0; k < KSPLIT; ++k) acc += p[k * stride + c];
    v[i] = acc; sum += acc; sq += acc * acc;
  }
#pragma unroll
  for (int d = 32; d; d >>= 1) { sum += __shfl_xor(sum, d); sq += __shfl_xor(sq, d); }
  __shared__ float ssum[4], ssq[4];
  int w = tid >> 6;
  if ((tid & 63) == 0) { ssum[w] = sum; ssq[w] = sq; }
  __syncthreads();
  sum = ssum[0] + ssum[1] + ssum[2] + ssum[3];
  sq  = ssq[0]  + ssq[1]  + ssq[2]  + ssq[3];
  float mean = sum * (1.0f / DI);
  float var  = sq * (1.0f / DI) - mean * mean;
  float rstd = rsqrtf(var + 1e-5f);
  float* o = out + (size_t)row * DI;
#pragma unroll
  for (int i = 0; i < 4; ++i) {
    int c = tid + i * 256;
    o[c] = (v[i] - mean) * rstd * gamma[c] + beta[c];
  }
}

extern "C" void kernel_launch(void* const* d_in, const int* in_sizes, int n_in,
                              void* d_out, int out_size, void* d_ws, size_t ws_size,
                              hipStream_t stream) {
  const float* img   = (const float*)d_in[0];
  const float* sent  = (const float*)d_in[1];
  const int*   mask  = (const int*)d_in[2];
  const float* Wq    = (const float*)d_in[3];
  const float* Wk    = (const float*)d_in[4];
  const float* Wv    = (const float*)d_in[5];
  const float* Wo    = (const float*)d_in[6];
  const float* gamma = (const float*)d_in[7];
  const float* beta  = (const float*)d_in[8];
  float* out = (float*)d_out;

  // workspace layout (~118 MB, lifetime-aliased)
  char* ws = (char*)d_ws;
  size_t o = 0;
  auto give = [&](size_t bytes) { char* p = ws + o; o += (bytes + 255) & ~(size_t)255; return p; };
  unsigned short* WqT = (unsigned short*)give((size_t)HD * DI * 2);       // [8192][1024]
  unsigned short* WkT = (unsigned short*)give((size_t)HD * DL * 2);       // [8192][768]
  unsigned short* WvT = (unsigned short*)give((size_t)HD * DL * 2);       // [8192][768]
  unsigned short* WoT = (unsigned short*)give((size_t)DI * HD * 2);       // [1024][8192]
  unsigned short* Qb  = (unsigned short*)give((size_t)BB * NQ * HD * 2);  // [1568][8192]
  unsigned short* Kb  = (unsigned short*)give((size_t)BB * NKK * HD * 2); // [1024][8192]
  unsigned short* Vb  = (unsigned short*)give((size_t)BB * NKK * HD * 2); // [1024][8192]
  // lifetime aliases (producers run strictly after the aliased buffer is dead)
  unsigned short* Vt  = WqT;             // [64][1024][128] bf16 = 16.78 MB (WqT dead after Q-proj)
  float*          S   = (float*)WkT;     // [64][196][128] f32 = 6.4 MB (WkT dead after K-proj)
  unsigned short* P   = WvT;             // [64][196][128] bf16 = 3.2 MB (WvT dead after V-proj)
  unsigned short* ctx = Qb;              // [1568][8192] bf16 (Q dead after score GEMM)
  float*          Oac4 = (float*)Kb;     // [KSPLIT][1568][1024] f32 = 25.7 MB over Kb+Vb
                                         // (Kb dead after score GEMM, Vb dead after V-transpose)

  dim3 tb(256);

  // 0) weight transpose+convert -> bf16 [N][K]
  k_transpose_f32_bf16<<<dim3(HD / 32, DI / 32), tb, 0, stream>>>(Wq, WqT, DI, HD);
  k_transpose_f32_bf16<<<dim3(HD / 32, DL / 32), tb, 0, stream>>>(Wk, WkT, DL, HD);
  k_transpose_f32_bf16<<<dim3(HD / 32, DL / 32), tb, 0, stream>>>(Wv, WvT, DL, HD);
  k_transpose_f32_bf16<<<dim3(DI / 32, HD / 32), tb, 0, stream>>>(Wo, WoT, HD, DI);

  // 1) Q = img @ Wq  [1568 x 8192], K = sent @ Wk, V = sent @ Wv  [1024 x 8192]
  k_gemm<false, true, false><<<dim3(HD / 128, (BB * NQ + 127) / 128, 1), tb, 0, stream>>>(
      img, WqT, Qb, nullptr, BB * NQ, HD, DI, DI, DI, HD, 0, 0, 0, 0, 0, 0);
  k_gemm<false, true, false><<<dim3(HD / 128, (BB * NKK) / 128, 1), tb, 0, stream>>>(
      sent, WkT, Kb, nullptr, BB * NKK, HD, DL, DL, DL, HD, 0, 0, 0, 0, 0, 0);
  k_gemm<false, true, false><<<dim3(HD / 128, (BB * NKK) / 128, 1), tb, 0, stream>>>(
      sent, WvT, Vb, nullptr, BB * NKK, HD, DL, DL, DL, HD, 0, 0, 0, 0, 0, 0);

  // 2) V -> Vt [z][d][key]
  k_transpose_v<<<dim3(DH / 32, NKK / 32, BB * HH), tb, 0, stream>>>(Vb, Vt);

  // 3) S[z] = Q_bh @ K_bh^T  (batched over 64 (b,h))
  k_gemm<true, false, false><<<dim3(NKK / 128, (NQ + 127) / 128, BB * HH), tb, 0, stream>>>(
      Qb, Kb, S, nullptr, NQ, NKK, DH, HD, HD, NKK,
      (long)NQ * HD, (long)DH, (long)NKK * HD, (long)DH, (long)HH * NQ * NKK, (long)NQ * NKK);

  // 4) P = softmax(S/32 masked)
  k_softmax<<<dim3(BB * HH * NQ / 4), tb, 0, stream>>>(S, P, mask);

  // 5) ctx[z] = P_bh @ V_bh  (via Vt as [d][key])
  k_gemm<true, true, false><<<dim3(DH / 128, (NQ + 127) / 128, BB * HH), tb, 0, stream>>>(
      P, Vt, ctx, nullptr, NQ, DH, NKK, NKK, NKK, HD,
      (long)HH * NQ * NKK, (long)NQ * NKK, (long)HH * DH * NKK, (long)DH * NKK,
      (long)NQ * HD, (long)DH);

  // 6) split-K out-projection: Oac4[z] = ctx[:, z*2048:(z+1)*2048] @ WoT[:, z*2048:(z+1)*2048]^T
  //    z = k-chunk (0..3); zb=0, zh=z -> aOff = z*2048, bOff = z*2048, cOff = z*M*DI
  k_gemm<true, false, false><<<dim3(DI / 128, (BB * NQ + 127) / 128, KSPLIT), tb, 0, stream>>>(
      ctx, WoT, Oac4, nullptr, BB * NQ, DI, HD / KSPLIT, HD, HD, DI,
      0, (long)(HD / KSPLIT), 0, (long)(HD / KSPLIT), 0, (long)(BB * NQ) * DI);

  // 7) fused reduce(4 partials) + residual + LayerNorm -> d_out
  k_layernorm_red<<<dim3(BB * NQ), tb, 0, stream>>>(Oac4, img, gamma, beta, out, BB * NQ);
}

// Round 3
// 210.688 us; speedup vs baseline: 2.6178x; 1.6636x over previous
//
#include <hip/hip_runtime.h>
#include <hip/hip_bf16.h>

// Problem constants (fixed by the reference)
#define BB 8      // batch
#define NQ 196    // image tokens (queries)
#define NKK 128   // sentence tokens (keys)
#define HH 8      // heads
#define DH 1024   // per-head dim
#define DI 1024   // image embed dim
#define DL 768    // sentence embed dim
#define HD 8192   // HH*DH
#define KSPLIT 8  // split-K factor for the out-projection GEMM

typedef __attribute__((ext_vector_type(8))) short short8;
typedef __attribute__((ext_vector_type(4))) float f32x4;

__device__ inline unsigned short f2bf(float f) {
  // RTNE f32 -> bf16 (inputs finite)
  unsigned int x = __float_as_uint(f);
  unsigned int r = (x + 0x7fffu + ((x >> 16) & 1u)) >> 16;
  return (unsigned short)r;
}

// async global->LDS, 16 B per lane; LDS dest = wave-uniform base + lane*16
__device__ inline void gload16(const unsigned short* g, unsigned short* l) {
  __builtin_amdgcn_global_load_lds(
      (const __attribute__((address_space(1))) void*)g,
      (__attribute__((address_space(3))) void*)l, 16, 0, 0);
}

// ---------------- f32 -> bf16 convert (8 elems/thread; n % 2048 == 0) ----------------
__global__ __launch_bounds__(256) void k_f32_to_bf16(
    const float* __restrict__ in, unsigned short* __restrict__ out, int n) {
  int i = (blockIdx.x * 256 + threadIdx.x) * 8;
  if (i >= n) return;
  float4 x = *reinterpret_cast<const float4*>(in + i);
  float4 y = *reinterpret_cast<const float4*>(in + i + 4);
  short8 v;
  v[0] = (short)f2bf(x.x); v[1] = (short)f2bf(x.y);
  v[2] = (short)f2bf(x.z); v[3] = (short)f2bf(x.w);
  v[4] = (short)f2bf(y.x); v[5] = (short)f2bf(y.y);
  v[6] = (short)f2bf(y.z); v[7] = (short)f2bf(y.w);
  *reinterpret_cast<short8*>(out + i) = v;
}

// ---------------- transpose f32[R][C] -> bf16[C][R] ----------------
__global__ __launch_bounds__(256) void k_transpose_f32_bf16(
    const float* __restrict__ in, unsigned short* __restrict__ out, int R, int C) {
  __shared__ float tile[32][33];
  int c0 = blockIdx.x * 32, r0 = blockIdx.y * 32;
  int tx = threadIdx.x & 31, ty = threadIdx.x >> 5;  // 32 x 8
#pragma unroll
  for (int k = 0; k < 32; k += 8)
    tile[ty + k][tx] = in[(size_t)(r0 + ty + k) * C + (c0 + tx)];
  __syncthreads();
#pragma unroll
  for (int k = 0; k < 32; k += 8)
    out[(size_t)(c0 + ty + k) * R + (r0 + tx)] = f2bf(tile[tx][ty + k]);
}

// ------- batched transpose of V: in[(b*128+key)*ld_in + h*1024 + d] -> Vt[z][d][key] -------
__global__ __launch_bounds__(256) void k_transpose_v(
    const unsigned short* __restrict__ Vp, unsigned short* __restrict__ Vt, int ld_in) {
  __shared__ unsigned short tile[32][34];
  int z = blockIdx.z, b = z >> 3, h = z & 7;
  const unsigned short* in = Vp + (size_t)b * NKK * ld_in + (size_t)h * DH;
  unsigned short* out = Vt + (size_t)z * DH * NKK;
  int d0 = blockIdx.x * 32, k0 = blockIdx.y * 32;
  int tx = threadIdx.x & 31, ty = threadIdx.x >> 5;
#pragma unroll
  for (int k = 0; k < 32; k += 8)
    tile[ty + k][tx] = in[(size_t)(k0 + ty + k) * ld_in + (d0 + tx)];
  __syncthreads();
#pragma unroll
  for (int k = 0; k < 32; k += 8)
    out[(size_t)(d0 + ty + k) * NKK + (k0 + tx)] = tile[tx][ty + k];
}

// ---------------- batched MFMA GEMM, global_load_lds + XOR-swizzled LDS ----------------
// C[m][n] = sum_k A[m][k] * B[n][k]   (A, B bf16, row strides lda/ldb elems)
// batch z -> (zb = z/8, zh = z%8); offsets in ELEMENTS.
// BM=BN=128, BK=64; 256 threads = 4 waves, each wave a 64x64 sub-tile (4x4 MFMA frags).
// LDS layout: linear [row][chunk] where the 16B chunk index is XOR-swizzled with (row&7)
// on BOTH the global source address (staging) and the ds_read address (rule #21).
template<bool C_BF16>
__global__ __launch_bounds__(256, 2) void k_gemm2(
    const unsigned short* __restrict__ A, const unsigned short* __restrict__ B,
    void* __restrict__ Cptr,
    int M, int N, int K, int lda, int ldb, int ldc,
    long aSB, long aSH, long bSB, long bSH, long cSB, long cSH) {
  __shared__ unsigned short As[128 * 64];
  __shared__ unsigned short Bs[128 * 64];

  const int tid = threadIdx.x;
  const int lane = tid & 63;
  const int wid = tid >> 6;
  const int wm = wid >> 1, wn = wid & 1;
  const int m_base = blockIdx.y * 128;
  const int n_base = blockIdx.x * 128;
  const int z = blockIdx.z, zb = z >> 3, zh = z & 7;
  const unsigned short* Ab = A + (size_t)zb * aSB + (size_t)zh * aSH;
  const unsigned short* Bb = B + (size_t)zb * bSB + (size_t)zh * bSH;

  // staging geometry: wave wid covers tile rows [wid*32, wid*32+32), 4 issues of 1024 B
  const int r0 = wid * 32 + (lane >> 3);                 // tile row at p=0
  const int sc8 = (((lane & 7) ^ (lane >> 3)) << 3);     // inverse-swizzled source col (elems)
  const unsigned short* aSrc[4];
  const unsigned short* bSrc[4];
#pragma unroll
  for (int p = 0; p < 4; ++p) {
    int rm = m_base + r0 + p * 8; rm = rm < M ? rm : M - 1;  // clamp (rows >= M never stored)
    aSrc[p] = Ab + (size_t)rm * lda + sc8;
    bSrc[p] = Bb + (size_t)(n_base + r0 + p * 8) * ldb + sc8;
  }

  const int fr = lane & 15;   // row-in-fragment
  const int q  = lane >> 4;   // k-quarter
  f32x4 acc[4][4] = {};

  for (int k0 = 0; k0 < K; k0 += 64) {
#pragma unroll
    for (int p = 0; p < 4; ++p) gload16(aSrc[p] + k0, &As[wid * 2048 + p * 512]);
#pragma unroll
    for (int p = 0; p < 4; ++p) gload16(bSrc[p] + k0, &Bs[wid * 2048 + p * 512]);
    __syncthreads();  // compiler emits vmcnt(0) drain before the barrier
#pragma unroll
    for (int kk = 0; kk < 2; ++kk) {
      short8 af[4], bfr[4];
#pragma unroll
      for (int mi = 0; mi < 4; ++mi) {
        int row = wm * 64 + mi * 16 + fr;
        int swz = ((kk * 4 + q) ^ (row & 7)) << 3;
        af[mi] = *reinterpret_cast<const short8*>(&As[row * 64 + swz]);
      }
#pragma unroll
      for (int ni = 0; ni < 4; ++ni) {
        int row = wn * 64 + ni * 16 + fr;
        int swz = ((kk * 4 + q) ^ (row & 7)) << 3;
        bfr[ni] = *reinterpret_cast<const short8*>(&Bs[row * 64 + swz]);
      }
#pragma unroll
      for (int mi = 0; mi < 4; ++mi)
#pragma unroll
        for (int ni = 0; ni < 4; ++ni)
          acc[mi][ni] = __builtin_amdgcn_mfma_f32_16x16x32_bf16(af[mi], bfr[ni], acc[mi][ni], 0, 0, 0);
    }
    __syncthreads();
  }

  // epilogue: C/D layout col = lane&15, row = (lane>>4)*4 + reg  [learn_hip m89/m91]
  const size_t cOff = (size_t)zb * cSB + (size_t)zh * cSH;
  const int rq = q * 4;
#pragma unroll
  for (int mi = 0; mi < 4; ++mi) {
#pragma unroll
    for (int ni = 0; ni < 4; ++ni) {
      int col = n_base + wn * 64 + ni * 16 + fr;
#pragma unroll
      for (int i = 0; i < 4; ++i) {
        int row = m_base + wm * 64 + mi * 16 + rq + i;
        if (row < M) {
          float val = acc[mi][ni][i];
          size_t off = cOff + (size_t)row * ldc + col;
          if constexpr (C_BF16) ((unsigned short*)Cptr)[off] = f2bf(val);
          else                  ((float*)Cptr)[off] = val;
        }
      }
    }
  }
}

// ---------------- masked softmax over 128 keys, one wave per row ----------------
__global__ __launch_bounds__(256) void k_softmax(
    const float* __restrict__ S, unsigned short* __restrict__ P, const int* __restrict__ mask) {
  int row = blockIdx.x * 4 + (threadIdx.x >> 6);
  if (row >= BB * HH * NQ) return;
  int lane = threadIdx.x & 63;
  int b = row / (HH * NQ);
  const float* s = S + (size_t)row * NKK;
  float s0 = s[lane] * 0.03125f;        // 1/sqrt(1024)
  float s1 = s[lane + 64] * 0.03125f;
  const int* mrow = mask + b * NKK;
  if (mrow[lane] == 0)      s0 = -1e30f;
  if (mrow[lane + 64] == 0) s1 = -1e30f;
  float mx = fmaxf(s0, s1);
#pragma unroll
  for (int d = 32; d; d >>= 1) mx = fmaxf(mx, __shfl_xor(mx, d));
  float e0 = __expf(s0 - mx), e1 = __expf(s1 - mx);
  float sum = e0 + e1;
#pragma unroll
  for (int d = 32; d; d >>= 1) sum += __shfl_xor(sum, d);
  float inv = 1.0f / sum;
  P[(size_t)row * NKK + lane]      = f2bf(e0 * inv);
  P[(size_t)row * NKK + lane + 64] = f2bf(e1 * inv);
}

// ------- fused split-K reduce + residual + LayerNorm over 1024, one block per row -------
__global__ __launch_bounds__(256) void k_layernorm_red(
    const float* __restrict__ Parts,   // [KSPLIT][M][DI] f32 partials
    const float* __restrict__ resid,   // img [M][DI]
    const float* __restrict__ gamma, const float* __restrict__ beta,
    float* __restrict__ out, int M) {
  int row = blockIdx.x;
  int tid = threadIdx.x;
  const size_t stride = (size_t)M * DI;
  const float* p = Parts + (size_t)row * DI;
  const float* r = resid + (size_t)row * DI;
  float v[4], sum = 0.f, sq = 0.f;
#pragma unroll
  for (int i = 0; i < 4; ++i) {
    int c = tid + i * 256;
    float acc = r[c];
#pragma unroll
    for (int k = 0; k < KSPLIT; ++k) acc += p[k * stride + c];
    v[i] = acc; sum += acc; sq += acc * acc;
  }
#pragma unroll
  for (int d = 32; d; d >>= 1) { sum += __shfl_xor(sum, d); sq += __shfl_xor(sq, d); }
  __shared__ float ssum[4], ssq[4];
  int w = tid >> 6;
  if ((tid & 63) == 0) { ssum[w] = sum; ssq[w] = sq; }
  __syncthreads();
  sum = ssum[0] + ssum[1] + ssum[2] + ssum[3];
  sq  = ssq[0]  + ssq[1]  + ssq[2]  + ssq[3];
  float mean = sum * (1.0f / DI);
  float var  = sq * (1.0f / DI) - mean * mean;
  float rstd = rsqrtf(var + 1e-5f);
  float* o = out + (size_t)row * DI;
#pragma unroll
  for (int i = 0; i < 4; ++i) {
    int c = tid + i * 256;
    o[c] = (v[i] - mean) * rstd * gamma[c] + beta[c];
  }
}

extern "C" void kernel_launch(void* const* d_in, const int* in_sizes, int n_in,
                              void* d_out, int out_size, void* d_ws, size_t ws_size,
                              hipStream_t stream) {
  const float* img   = (const float*)d_in[0];
  const float* sent  = (const float*)d_in[1];
  const int*   mask  = (const int*)d_in[2];
  const float* Wq    = (const float*)d_in[3];
  const float* Wk    = (const float*)d_in[4];
  const float* Wv    = (const float*)d_in[5];
  const float* Wo    = (const float*)d_in[6];
  const float* gamma = (const float*)d_in[7];
  const float* beta  = (const float*)d_in[8];
  float* out = (float*)d_out;

  // ---- workspace map (hand-placed, lifetime-aliased; peak ~104 MB) ----
  // stages: s0 conv+transp | s1 Qproj | s2 KVproj | s3 Vtrans | s4 score
  //         s5 softmax | s6 PV | s7 outproj | s8 LN
  char* ws = (char*)d_ws;
  unsigned short* WoT   = (unsigned short*)(ws);                  // 16.78M  s0-s7
  unsigned short* WkvT  = (unsigned short*)(ws + 16777216);       // 25.17M  s0-s2
  unsigned short* Vt    = (unsigned short*)(ws + 16777216);       // 16.78M  s3-s6 (over WkvT)
  float*          S     = (float*)         (ws + 33554432);       //  6.42M  s4-s5
  unsigned short* P     = (unsigned short*)(ws + 39976960);       //  3.21M  s5-s6
  float*          Oac   = (float*)         (ws + 16777216);       // 51.38M  s7-s8 (over WkvT/Vt/S/P)
  unsigned short* Qb    = (unsigned short*)(ws + 43188224);       // 25.69M  s1-s4
  unsigned short* KVb   = (unsigned short*)(ws + 68878336);       // 33.55M  s2-s4
  unsigned short* WqT   = (unsigned short*)(ws + 68878336);       // 16.78M  s0-s1 (pre-KVb)
  unsigned short* imgB  = (unsigned short*)(ws + 85655552);       //  3.21M  s0-s1 (pre-KVb)
  unsigned short* ctx   = (unsigned short*)(ws + 68878336);       // 25.69M  s6-s7 (over KVb)
  unsigned short* sentB = (unsigned short*)(ws + 102432768);      //  1.57M  s0-s2

  dim3 tb(256);

  // s0) input convert + weight transpose/convert -> bf16 [N][K]
  k_f32_to_bf16<<<dim3((BB * NQ * DI) / 2048), tb, 0, stream>>>(img, imgB, BB * NQ * DI);
  k_f32_to_bf16<<<dim3((BB * NKK * DL) / 2048), tb, 0, stream>>>(sent, sentB, BB * NKK * DL);
  k_transpose_f32_bf16<<<dim3(HD / 32, DI / 32), tb, 0, stream>>>(Wq, WqT, DI, HD);
  k_transpose_f32_bf16<<<dim3(HD / 32, DL / 32), tb, 0, stream>>>(Wk, WkvT, DL, HD);
  k_transpose_f32_bf16<<<dim3(HD / 32, DL / 32), tb, 0, stream>>>(Wv, WkvT + (size_t)HD * DL, DL, HD);
  k_transpose_f32_bf16<<<dim3(DI / 32, HD / 32), tb, 0, stream>>>(Wo, WoT, HD, DI);

  // s1) Q = imgB @ WqT^T  [1568 x 8192]
  k_gemm2<true><<<dim3(HD / 128, 13, 1), tb, 0, stream>>>(
      imgB, WqT, Qb, BB * NQ, HD, DI, DI, DI, HD, 0, 0, 0, 0, 0, 0);

  // s2) KV = sentB @ WkvT^T  [1024 x 16384]  (cols 0..8191 = K, 8192.. = V)
  k_gemm2<true><<<dim3((2 * HD) / 128, (BB * NKK) / 128, 1), tb, 0, stream>>>(
      sentB, WkvT, KVb, BB * NKK, 2 * HD, DL, DL, DL, 2 * HD, 0, 0, 0, 0, 0, 0);

  // s3) V -> Vt [z][d][key]
  k_transpose_v<<<dim3(DH / 32, NKK / 32, BB * HH), tb, 0, stream>>>(KVb + HD, Vt, 2 * HD);

  // s4) S[z] = Q_bh @ K_bh^T  (batched over 64 (b,h))
  k_gemm2<false><<<dim3(1, 2, BB * HH), tb, 0, stream>>>(
      Qb, KVb, S, NQ, NKK, DH, HD, 2 * HD, NKK,
      (long)NQ * HD, (long)DH, (long)NKK * 2 * HD, (long)DH, (long)HH * NQ * NKK, (long)NQ * NKK);

  // s5) P = softmax(S/32 masked)
  k_softmax<<<dim3(BB * HH * NQ / 4), tb, 0, stream>>>(S, P, mask);

  // s6) ctx[z] = P_bh @ V_bh  (via Vt as [d][key])
  k_gemm2<true><<<dim3(DH / 128, 2, BB * HH), tb, 0, stream>>>(
      P, Vt, ctx, NQ, DH, NKK, NKK, NKK, HD,
      (long)HH * NQ * NKK, (long)NQ * NKK, (long)HH * DH * NKK, (long)DH * NKK,
      (long)NQ * HD, (long)DH);

  // s7) split-K out-projection: Oac[z] = ctx[:, z*1024:...] @ WoT[:, z*1024:...]^T
  k_gemm2<false><<<dim3(DI / 128, 13, KSPLIT), tb, 0, stream>>>(
      ctx, WoT, Oac, BB * NQ, DI, HD / KSPLIT, HD, HD, DI,
      0, (long)(HD / KSPLIT), 0, (long)(HD / KSPLIT), 0, (long)(BB * NQ) * DI);

  // s8) fused reduce(8 partials) + residual + LayerNorm -> d_out
  k_layernorm_red<<<dim3(BB * NQ), tb, 0, stream>>>(Oac, img, gamma, beta, out, BB * NQ);
}